// Round 1
// baseline (457.294 us; speedup 1.0000x reference)
//
#include <hip/hip_runtime.h>
#include <hip/hip_bf16.h>

#define NN 8192
#define DD 128

typedef __attribute__((ext_vector_type(4))) float f32x4;
typedef __attribute__((ext_vector_type(8))) short s16x8;
typedef __attribute__((ext_vector_type(4))) short s16x4;

__device__ inline short bfbits(float f) {
    // fp32 -> bf16 (RNE) bit pattern
    unsigned u = __builtin_bit_cast(unsigned, f);
    u += 0x7fffu + ((u >> 16) & 1u);
    return (short)(u >> 16);
}

__device__ inline s16x4 cvt4(f32x4 a) {
    s16x4 r;
    r[0] = bfbits(a[0]); r[1] = bfbits(a[1]); r[2] = bfbits(a[2]); r[3] = bfbits(a[3]);
    return r;
}

__device__ inline s16x8 cvt8(f32x4 a, f32x4 b) {
    s16x8 r;
    r[0] = bfbits(a[0]); r[1] = bfbits(a[1]); r[2] = bfbits(a[2]); r[3] = bfbits(a[3]);
    r[4] = bfbits(b[0]); r[5] = bfbits(b[1]); r[6] = bfbits(b[2]); r[7] = bfbits(b[3]);
    return r;
}

#define WST 132  // LDS stride (shorts) for W tile: kills 8-way bank conflicts

// ================= NEW PATH =================
// Kernel 1 (prep): interleaved role-split blocks.
//  - deg blocks (8 of every 16): 32 adj rows each; compute row sums AND write bf16(adj)
//    into adjc pre-laid-out as the agg LDS tile image: tile = 32 rows x 128 cols,
//    slot(row, cd) = row*16 + (cd ^ (row & 15)), 8 shorts/slot  (8 KB per tile).
//    Wave-level writes cover full 256 B row-stripes -> full-line coalesced.
//  - proj blocks: x@W (UNscaled, dinv deferred) -> hU fp32 in h2f fragment order.
__global__ __launch_bounds__(512, 2) void prep_kernel(const float* __restrict__ adj,
                                                      const float* __restrict__ x,
                                                      const float* __restrict__ w,
                                                      float* __restrict__ dinv,
                                                      unsigned short* __restrict__ adjc,
                                                      float* __restrict__ hU) {
    __shared__ short lds_w[128 * WST];
    const int tid = threadIdx.x;
    const int grp = blockIdx.x >> 4;
    const int sub = blockIdx.x & 15;   // interleave deg/proj in groups of 8 (XCD balance)

    if (sub < 8) {
        // ---- deg + bf16 convert: rows [mb*32, mb*32+32) ----
        const int mb   = grp * 8 + sub;          // 0..255
        const int row0 = tid >> 5;               // 0..15
        const int off0 = (tid & 31) << 2;        // col offset within 128-tile
        const int cd   = (tid & 31) >> 1;        // 16B chunk within row
        const int hh   = tid & 1;                // which 8B half of the chunk
        const int so0  = ((row0 << 4) + (cd ^ row0)) * 8 + hh * 4;          // shorts
        const int so1  = (((16 + row0) << 4) + (cd ^ row0)) * 8 + hh * 4;

        const float* ap0 = adj + (size_t)(mb * 32 + row0) * NN + off0;
        const float* ap1 = ap0 + (size_t)16 * NN;
        unsigned short* cb = adjc + (size_t)mb * (64 * 4096);  // 64 tiles * 4096 shorts

        f32x4 s0 = {0.f, 0.f, 0.f, 0.f};
        f32x4 s1 = {0.f, 0.f, 0.f, 0.f};
        #pragma unroll 4
        for (int t = 0; t < 64; ++t) {
            f32x4 v0 = *(const f32x4*)(ap0 + t * 128);
            f32x4 v1 = *(const f32x4*)(ap1 + t * 128);
            s0 += v0; s1 += v1;
            *(s16x4*)(cb + (size_t)t * 4096 + so0) = cvt4(v0);
            *(s16x4*)(cb + (size_t)t * 4096 + so1) = cvt4(v1);
        }
        float r0 = s0[0] + s0[1] + s0[2] + s0[3];
        float r1 = s1[0] + s1[1] + s1[2] + s1[3];
        #pragma unroll
        for (int off = 16; off; off >>= 1) {
            r0 += __shfl_xor(r0, off, 32);
            r1 += __shfl_xor(r1, off, 32);
        }
        if ((tid & 31) == 0) {
            dinv[mb * 32 + row0]      = (r0 > 0.f) ? rsqrtf(r0) : 0.f;
            dinv[mb * 32 + 16 + row0] = (r1 > 0.f) ? rsqrtf(r1) : 0.f;
        }
    } else {
        // ---- proj: rows [pb*32, pb*32+32), unscaled, fp32 fragment-order out ----
        const int pb   = grp * 8 + (sub - 8);    // 0..255
        const int lane = tid & 63;
        const int wave = tid >> 6;               // 0..7
        const int r    = lane & 15;
        const int q    = lane >> 4;
        const int j0   = pb * 32 + (wave >> 2) * 16;
        const int n0   = (wave & 3) << 5;

        #pragma unroll
        for (int i = 0; i < 8; ++i) {
            int gi = i * 512 + tid;
            int k  = gi >> 5;
            int n4 = (gi & 31) << 2;
            f32x4 v = *(const f32x4*)(w + (size_t)k * DD + n4);
            *(s16x4*)&lds_w[k * WST + n4] = cvt4(v);
        }
        __syncthreads();

        const float* xp = x + (size_t)(j0 + r) * DD + (q << 3);
        f32x4 acc0 = {0.f, 0.f, 0.f, 0.f};
        f32x4 acc1 = {0.f, 0.f, 0.f, 0.f};

        #pragma unroll
        for (int k = 0; k < DD; k += 32) {
            f32x4 a0 = *(const f32x4*)(xp + k);
            f32x4 a1 = *(const f32x4*)(xp + k + 4);
            s16x8 af = cvt8(a0, a1);
            const int kb = k + (q << 3);
            s16x8 b0, b1;
            #pragma unroll
            for (int jj = 0; jj < 8; ++jj) {
                b0[jj] = lds_w[(kb + jj) * WST + n0 + r];
                b1[jj] = lds_w[(kb + jj) * WST + n0 + 16 + r];
            }
            acc0 = __builtin_amdgcn_mfma_f32_16x16x32_bf16(af, b0, acc0, 0, 0, 0);
            acc1 = __builtin_amdgcn_mfma_f32_16x16x32_bf16(af, b1, acc1, 0, 0, 0);
        }

        // C/D: col = lane&15 (n), row = q*4+rr (j). fp32 scatter into fragment order.
        #pragma unroll
        for (int rr = 0; rr < 4; ++rr) {
            const int j  = j0 + (q << 2) + rr;
            const int kg = j >> 5, qp = (j >> 3) & 3, jj = j & 7;
            #pragma unroll
            for (int half = 0; half < 2; ++half) {
                const int n = n0 + half * 16 + r;
                const int f = n >> 4;
                const int lanep = qp * 16 + (n & 15);
                hU[(((size_t)((f << 8) | kg) << 6) | lanep) * 8 + jj] =
                    (half ? acc1[rr] : acc0[rr]);
            }
        }
    }
}

// Kernel 2 (scale): h2f = bf16(dinv[j] * hU), identical numerics to the old proj epilogue.
__global__ __launch_bounds__(256) void scale_kernel(const float* __restrict__ hU,
                                                    const float* __restrict__ dinv,
                                                    unsigned short* __restrict__ h2f) {
    const int s  = blockIdx.x * 256 + threadIdx.x;   // slot id, 131072 total
    const int kg = (s >> 6) & 255;
    const int qp = (s >> 4) & 3;
    const int j0 = (kg << 5) + (qp << 3);            // 8 consecutive j per slot
    f32x4 a  = *(const f32x4*)(hU + (size_t)s * 8);
    f32x4 b  = *(const f32x4*)(hU + (size_t)s * 8 + 4);
    f32x4 d0 = *(const f32x4*)(dinv + j0);
    f32x4 d1 = *(const f32x4*)(dinv + j0 + 4);
    s16x8 o;
    o[0] = bfbits(a[0] * d0[0]); o[1] = bfbits(a[1] * d0[1]);
    o[2] = bfbits(a[2] * d0[2]); o[3] = bfbits(a[3] * d0[3]);
    o[4] = bfbits(b[0] * d1[0]); o[5] = bfbits(b[1] * d1[1]);
    o[6] = bfbits(b[2] * d1[2]); o[7] = bfbits(b[3] * d1[3]);
    *(s16x8*)(h2f + (size_t)s * 8) = o;
}

// Kernel 3 (agg2): BM=32, 8 waves, KSPLIT=2. A tiles arrive pre-converted/pre-swizzled:
// one global_load_lds dwordx4 per thread per tile (zero staging VALU, zero ds_write).
__device__ inline void stage_tile(const unsigned short* __restrict__ src,
                                  short* lds_base, int tid) {
    const __attribute__((address_space(1))) unsigned int* g =
        (const __attribute__((address_space(1))) unsigned int*)src + ((size_t)tid << 2);
    __attribute__((address_space(3))) unsigned int* l =
        (__attribute__((address_space(3))) unsigned int*)(lds_base + ((tid >> 6) << 9));
    // dst = wave-uniform base + lane*16 (HW rule); 16B width
    __builtin_amdgcn_global_load_lds(g, l, 16, 0, 0);
}

__global__ __launch_bounds__(512, 4) void agg2_kernel(const unsigned short* __restrict__ adjc,
                                                      const unsigned short* __restrict__ h2f,
                                                      float* __restrict__ part) {
    __shared__ __align__(16) short lds_a[2][4096];   // 2 x 8 KB tiles
    const int tid  = threadIdx.x;
    const int lane = tid & 63;
    const int wave = tid >> 6;        // 0..7
    const int r    = lane & 15;
    const int q    = lane >> 4;
    const int w4   = wave & 3;        // n-quadrant
    const int half = wave >> 2;       // m-half of the 32-row tile
    const int mb   = blockIdx.x;      // 0..255
    const int by   = blockIdx.y;      // 0..1 (K split)

    const unsigned short* asrc = adjc + (size_t)mb * (64 * 4096) + (size_t)by * (32 * 4096);
    const unsigned short* bb0 =
        h2f + (((size_t)(w4 * 2)     * 256 + (size_t)by * 128) * 64 + lane) * 8;
    const unsigned short* bb1 =
        h2f + (((size_t)(w4 * 2 + 1) * 256 + (size_t)by * 128) * 64 + lane) * 8;

    f32x4 acc0 = {0.f, 0.f, 0.f, 0.f};
    f32x4 acc1 = {0.f, 0.f, 0.f, 0.f};

    stage_tile(asrc, lds_a[0], tid);
    __syncthreads();

    for (int t = 0; t < 32; ++t) {
        const short* lcur = lds_a[t & 1];

        // B first (L2-resident; MFMA's vmcnt wait then excludes the staging load)
        s16x8 br0[4], br1[4];
        #pragma unroll
        for (int s = 0; s < 4; ++s) {
            br0[s] = *(const s16x8*)(bb0 + (size_t)(t * 4 + s) * 512);
            br1[s] = *(const s16x8*)(bb1 + (size_t)(t * 4 + s) * 512);
        }
        if (t + 1 < 32) stage_tile(asrc + (size_t)(t + 1) * 4096, lds_a[(t + 1) & 1], tid);

        #pragma unroll
        for (int s = 0; s < 4; ++s) {
            const int slot = (((half << 4) | r) << 4) + (((s << 2) + q) ^ r);
            s16x8 af = *(const s16x8*)(lcur + slot * 8);
            acc0 = __builtin_amdgcn_mfma_f32_16x16x32_bf16(af, br0[s], acc0, 0, 0, 0);
            acc1 = __builtin_amdgcn_mfma_f32_16x16x32_bf16(af, br1[s], acc1, 0, 0, 0);
        }
        __syncthreads();  // drains vmcnt(0): next tile staged + buffers in lockstep
    }

    // C/D: col = lane&15 (n), row = q*4+rr (m)
    #pragma unroll
    for (int rr = 0; rr < 4; ++rr) {
        const int m = (mb << 5) + (half << 4) + (q << 2) + rr;
        const int n = (w4 << 5) + r;
        float* p = part + (size_t)by * (NN * DD);
        p[(size_t)m * DD + n]      = acc0[rr];
        p[(size_t)m * DD + n + 16] = acc1[rr];
    }
}

// Kernel 4: out = dinv[m]*(p0+p1) + bias
__global__ __launch_bounds__(256) void reduce_kernel(const float* __restrict__ part,
                                                     const float* __restrict__ dinv,
                                                     const float* __restrict__ bias,
                                                     float* __restrict__ out) {
    const int idx = blockIdx.x * 256 + threadIdx.x;   // f32x4 index, NN*DD/4 total
    const f32x4 a = ((const f32x4*)part)[idx];
    const f32x4 b = ((const f32x4*)part)[idx + NN * DD / 4];
    const float dv = dinv[idx >> 5];
    const f32x4 bi = *(const f32x4*)(bias + ((idx & 31) << 2));
    f32x4 s = a + b;
    f32x4 o;
    o[0] = s[0] * dv + bi[0]; o[1] = s[1] * dv + bi[1];
    o[2] = s[2] * dv + bi[2]; o[3] = s[3] * dv + bi[3];
    ((f32x4*)out)[idx] = o;
}

// ================= FALLBACK PATH (small workspace) =================
__global__ __launch_bounds__(256) void deg_kernel(const float* __restrict__ adj,
                                                  float* __restrict__ dinv) {
    const int lane = threadIdx.x & 63;
    const int row  = (blockIdx.x << 2) + (threadIdx.x >> 6);
    const float* r = adj + (size_t)row * NN;
    f32x4 s = {0.f, 0.f, 0.f, 0.f};
    #pragma unroll 4
    for (int it = 0; it < 32; ++it) {
        f32x4 v = *(const f32x4*)(r + it * 256 + (lane << 2));
        s += v;
    }
    float sum = s[0] + s[1] + s[2] + s[3];
    #pragma unroll
    for (int off = 32; off; off >>= 1) sum += __shfl_xor(sum, off, 64);
    if (lane == 0) dinv[row] = (sum > 0.f) ? rsqrtf(sum) : 0.f;
}

__global__ __launch_bounds__(256) void proj_kernel(const float* __restrict__ x,
                                                   const float* __restrict__ w,
                                                   const float* __restrict__ dinv,
                                                   unsigned short* __restrict__ h2f) {
    __shared__ short lds_w[128 * WST];
    const int tid  = threadIdx.x;
    const int lane = tid & 63;
    const int wave = tid >> 6;
    const int j0   = blockIdx.x << 4;
    const int n0   = wave << 5;
    const int r    = lane & 15;
    const int q    = lane >> 4;
    #pragma unroll
    for (int i = 0; i < 16; ++i) {
        int gi = i * 256 + tid;
        int k  = gi >> 5;
        int n4 = (gi & 31) << 2;
        f32x4 v = *(const f32x4*)(w + (size_t)k * DD + n4);
        *(s16x4*)&lds_w[k * WST + n4] = cvt4(v);
    }
    __syncthreads();
    const float* xp = x + (size_t)(j0 + r) * DD + (q << 3);
    f32x4 acc0 = {0.f, 0.f, 0.f, 0.f};
    f32x4 acc1 = {0.f, 0.f, 0.f, 0.f};
    #pragma unroll
    for (int k = 0; k < DD; k += 32) {
        f32x4 a0 = *(const f32x4*)(xp + k);
        f32x4 a1 = *(const f32x4*)(xp + k + 4);
        s16x8 af = cvt8(a0, a1);
        const int kb = k + (q << 3);
        s16x8 b0, b1;
        #pragma unroll
        for (int jj = 0; jj < 8; ++jj) {
            b0[jj] = lds_w[(kb + jj) * WST + n0 + r];
            b1[jj] = lds_w[(kb + jj) * WST + n0 + 16 + r];
        }
        acc0 = __builtin_amdgcn_mfma_f32_16x16x32_bf16(af, b0, acc0, 0, 0, 0);
        acc1 = __builtin_amdgcn_mfma_f32_16x16x32_bf16(af, b1, acc1, 0, 0, 0);
    }
    #pragma unroll
    for (int rr = 0; rr < 4; ++rr) {
        const int j = j0 + (q << 2) + rr;
        const float dv = dinv[j];
        const int kg = j >> 5, qp = (j >> 3) & 3, jj = j & 7;
        #pragma unroll
        for (int half = 0; half < 2; ++half) {
            const int n = n0 + half * 16 + r;
            const int f = n >> 4;
            const int lanep = qp * 16 + (n & 15);
            const float v = (half ? acc1[rr] : acc0[rr]) * dv;
            h2f[((((size_t)f << 8) + kg) << 6 | lanep) * 8 + jj] = (unsigned short)bfbits(v);
        }
    }
}

template <int KSPLIT>
__global__ __launch_bounds__(256, 4) void agg_kernel(const float* __restrict__ adj,
                                                     const unsigned short* __restrict__ h2f,
                                                     const float* __restrict__ dinv,
                                                     const float* __restrict__ bias,
                                                     float* __restrict__ dst) {
    constexpr int KS    = NN / KSPLIT;
    constexpr int TILES = KS / 128;
    __shared__ short lds_a[2][16 * 16 * 8];
    const int tid  = threadIdx.x;
    const int lane = tid & 63;
    const int wave = tid >> 6;
    const int r    = lane & 15;
    const int q    = lane >> 4;
    const int m0   = blockIdx.x << 4;
    const int k0   = blockIdx.y * KS;
    const int row0 = tid >> 5;
    const int off0 = (tid & 31) << 2;
    const int cd   = (tid & 31) >> 1;
    const int hh   = tid & 1;
    const int so0  = ((row0 << 4) + (cd ^ row0)) * 8 + hh * 4;
    const int so1  = (((8 + row0) << 4) + (cd ^ (8 + row0))) * 8 + hh * 4;
    const float* ap0 = adj + (size_t)(m0 + row0) * NN + k0 + off0;
    const float* ap1 = adj + (size_t)(m0 + 8 + row0) * NN + k0 + off0;
    const unsigned short* bb0 = h2f + (((size_t)(wave * 2)     * 256 + (k0 >> 5)) * 64 + lane) * 8;
    const unsigned short* bb1 = h2f + (((size_t)(wave * 2 + 1) * 256 + (k0 >> 5)) * 64 + lane) * 8;
    f32x4 acc0 = {0.f, 0.f, 0.f, 0.f};
    f32x4 acc1 = {0.f, 0.f, 0.f, 0.f};
    {
        f32x4 v0 = *(const f32x4*)(ap0);
        f32x4 v1 = *(const f32x4*)(ap1);
        *(s16x4*)&lds_a[0][so0] = cvt4(v0);
        *(s16x4*)&lds_a[0][so1] = cvt4(v1);
    }
    __syncthreads();
    for (int t = 0; t < TILES; ++t) {
        const short* lcur = lds_a[t & 1];
        short* lnxt = (short*)lds_a[(t + 1) & 1];
        s16x8 br0[4], br1[4];
        #pragma unroll
        for (int s = 0; s < 4; ++s) {
            br0[s] = *(const s16x8*)(bb0 + (size_t)(t * 4 + s) * 512);
            br1[s] = *(const s16x8*)(bb1 + (size_t)(t * 4 + s) * 512);
        }
        f32x4 v0, v1;
        if (t + 1 < TILES) {
            v0 = *(const f32x4*)(ap0 + (t + 1) * 128);
            v1 = *(const f32x4*)(ap1 + (t + 1) * 128);
        }
        #pragma unroll
        for (int s = 0; s < 4; ++s) {
            const int slot = (r << 4) + (((s << 2) + q) ^ r);
            s16x8 af = *(const s16x8*)(lcur + slot * 8);
            acc0 = __builtin_amdgcn_mfma_f32_16x16x32_bf16(af, br0[s], acc0, 0, 0, 0);
            acc1 = __builtin_amdgcn_mfma_f32_16x16x32_bf16(af, br1[s], acc1, 0, 0, 0);
        }
        if (t + 1 < TILES) {
            *(s16x4*)(lnxt + so0) = cvt4(v0);
            *(s16x4*)(lnxt + so1) = cvt4(v1);
        }
        __syncthreads();
    }
    #pragma unroll
    for (int rr = 0; rr < 4; ++rr) {
        const int m = m0 + (q << 2) + rr;
        const int n = (wave << 5) + r;
        const float dv = dinv[m];
        dst[(size_t)m * DD + n]      = acc0[rr] * dv + bias[n];
        dst[(size_t)m * DD + n + 16] = acc1[rr] * dv + bias[n + 16];
    }
}

extern "C" void kernel_launch(void* const* d_in, const int* in_sizes, int n_in,
                              void* d_out, int out_size, void* d_ws, size_t ws_size,
                              hipStream_t stream) {
    const float* x    = (const float*)d_in[0];   // [8192][128]
    const float* adj  = (const float*)d_in[1];   // [8192][8192]
    const float* w    = (const float*)d_in[2];   // [128][128]
    const float* bias = (const float*)d_in[3];   // [128]
    float* out = (float*)d_out;                  // [8192][128]

    // ws layout: dinv 32KB | h2f 2MB | hU 4MB | adjc 128MB | part 8MB
    float* dinv         = (float*)d_ws;
    unsigned short* h2f = (unsigned short*)((char*)d_ws + 32 * 1024);
    float* hU           = (float*)((char*)d_ws + 32 * 1024 + 2 * 1024 * 1024);
    unsigned short* adjc = (unsigned short*)((char*)d_ws + 32 * 1024 + 6 * 1024 * 1024);
    float* part         = (float*)((char*)adjc + 134217728ull);
    const size_t need_new = 32 * 1024 + 6 * 1024 * 1024 + 134217728ull + 8 * 1024 * 1024;

    if (ws_size >= need_new) {
        prep_kernel<<<512, 512, 0, stream>>>(adj, x, w, dinv, adjc, hU);
        scale_kernel<<<512, 256, 0, stream>>>(hU, dinv, h2f);
        agg2_kernel<<<dim3(256, 2), 512, 0, stream>>>(adjc, h2f, part);
        reduce_kernel<<<NN * DD / 4 / 256, 256, 0, stream>>>(part, dinv, bias, out);
    } else {
        deg_kernel<<<NN / 4, 256, 0, stream>>>(adj, dinv);
        proj_kernel<<<NN / 16, 256, 0, stream>>>(x, w, dinv, h2f);
        agg_kernel<1><<<dim3(NN / 16, 1), 256, 0, stream>>>(adj, h2f, dinv, bias, out);
    }
}

// Round 2
// 451.139 us; speedup vs baseline: 1.0136x; 1.0136x over previous
//
#include <hip/hip_runtime.h>
#include <hip/hip_bf16.h>

#define NN 8192
#define DD 128

typedef __attribute__((ext_vector_type(4))) float f32x4;
typedef __attribute__((ext_vector_type(8))) short s16x8;
typedef __attribute__((ext_vector_type(4))) short s16x4;

__device__ inline short bfbits(float f) {
    // fp32 -> bf16 (RNE) bit pattern
    unsigned u = __builtin_bit_cast(unsigned, f);
    u += 0x7fffu + ((u >> 16) & 1u);
    return (short)(u >> 16);
}

__device__ inline s16x4 cvt4(f32x4 a) {
    s16x4 r;
    r[0] = bfbits(a[0]); r[1] = bfbits(a[1]); r[2] = bfbits(a[2]); r[3] = bfbits(a[3]);
    return r;
}

__device__ inline s16x8 cvt8(f32x4 a, f32x4 b) {
    s16x8 r;
    r[0] = bfbits(a[0]); r[1] = bfbits(a[1]); r[2] = bfbits(a[2]); r[3] = bfbits(a[3]);
    r[4] = bfbits(b[0]); r[5] = bfbits(b[1]); r[6] = bfbits(b[2]); r[7] = bfbits(b[3]);
    return r;
}

#define WST 132  // LDS stride (shorts) for W tile: kills 8-way bank conflicts

// ================= Kernel 1 (prep2): role-split deg + unscaled proj =================
// 4:1 block interleave (co-prime with 8 XCDs). deg = old deg_kernel body (4 rows/block).
// proj = old proj_kernel but dinv-scale DEFERRED: writes fp32 hU in fragment order.
__global__ __launch_bounds__(256) void prep2_kernel(const float* __restrict__ adj,
                                                    const float* __restrict__ x,
                                                    const float* __restrict__ w,
                                                    float* __restrict__ dinv,
                                                    float* __restrict__ hU) {
    __shared__ short lds_w[128 * WST];
    const int tid = threadIdx.x;
    const int sub = blockIdx.x % 5;
    const int grp = blockIdx.x / 5;

    if (sub < 4) {
        // ---- deg: row sums for 4 rows (identical to proven deg_kernel) ----
        const int db   = grp * 4 + sub;            // 0..2047
        const int lane = tid & 63;
        const int row  = (db << 2) + (tid >> 6);
        const float* r = adj + (size_t)row * NN;

        f32x4 s = {0.f, 0.f, 0.f, 0.f};
        #pragma unroll 4
        for (int it = 0; it < 32; ++it) {
            f32x4 v = *(const f32x4*)(r + it * 256 + (lane << 2));
            s += v;
        }
        float sum = s[0] + s[1] + s[2] + s[3];
        #pragma unroll
        for (int off = 32; off; off >>= 1) sum += __shfl_xor(sum, off, 64);
        if (lane == 0) dinv[row] = (sum > 0.f) ? rsqrtf(sum) : 0.f;
    } else {
        // ---- proj: rows [pb*16, pb*16+16), UNscaled, fp32 fragment-order out ----
        const int pb   = grp;                      // 0..511
        const int lane = tid & 63;
        const int wave = tid >> 6;
        const int j0   = pb << 4;
        const int n0   = wave << 5;
        const int r    = lane & 15;
        const int q    = lane >> 4;

        #pragma unroll
        for (int i = 0; i < 16; ++i) {
            int gi = i * 256 + tid;
            int k  = gi >> 5;
            int n4 = (gi & 31) << 2;
            f32x4 v = *(const f32x4*)(w + (size_t)k * DD + n4);
            *(s16x4*)&lds_w[k * WST + n4] = cvt4(v);
        }
        __syncthreads();

        const float* xp = x + (size_t)(j0 + r) * DD + (q << 3);
        f32x4 acc0 = {0.f, 0.f, 0.f, 0.f};
        f32x4 acc1 = {0.f, 0.f, 0.f, 0.f};

        #pragma unroll
        for (int k = 0; k < DD; k += 32) {
            f32x4 a0 = *(const f32x4*)(xp + k);
            f32x4 a1 = *(const f32x4*)(xp + k + 4);
            s16x8 af = cvt8(a0, a1);
            const int kb = k + (q << 3);
            s16x8 b0, b1;
            #pragma unroll
            for (int jj = 0; jj < 8; ++jj) {
                b0[jj] = lds_w[(kb + jj) * WST + n0 + r];
                b1[jj] = lds_w[(kb + jj) * WST + n0 + 16 + r];
            }
            acc0 = __builtin_amdgcn_mfma_f32_16x16x32_bf16(af, b0, acc0, 0, 0, 0);
            acc1 = __builtin_amdgcn_mfma_f32_16x16x32_bf16(af, b1, acc1, 0, 0, 0);
        }

        // C/D: col = lane&15 (n), row = q*4+rr (j). fp32 scatter into fragment order.
        #pragma unroll
        for (int rr = 0; rr < 4; ++rr) {
            const int j  = j0 + (q << 2) + rr;
            const int kg = j >> 5, qp = (j >> 3) & 3, jj = j & 7;
            #pragma unroll
            for (int half = 0; half < 2; ++half) {
                const int n = n0 + half * 16 + r;
                const int f = n >> 4;
                const int lanep = qp * 16 + (n & 15);
                hU[(((size_t)((f << 8) | kg) << 6) | lanep) * 8 + jj] =
                    (half ? acc1[rr] : acc0[rr]);
            }
        }
    }
}

// ================= Kernel 2 (scale): h2f = bf16(dinv[j] * hU) — proven in round 1 ====
__global__ __launch_bounds__(256) void scale_kernel(const float* __restrict__ hU,
                                                    const float* __restrict__ dinv,
                                                    unsigned short* __restrict__ h2f) {
    const int s  = blockIdx.x * 256 + threadIdx.x;   // slot id, 131072 total
    const int kg = (s >> 6) & 255;
    const int qp = (s >> 4) & 3;
    const int j0 = (kg << 5) + (qp << 3);            // 8 consecutive j per slot
    f32x4 a  = *(const f32x4*)(hU + (size_t)s * 8);
    f32x4 b  = *(const f32x4*)(hU + (size_t)s * 8 + 4);
    f32x4 d0 = *(const f32x4*)(dinv + j0);
    f32x4 d1 = *(const f32x4*)(dinv + j0 + 4);
    s16x8 o;
    o[0] = bfbits(a[0] * d0[0]); o[1] = bfbits(a[1] * d0[1]);
    o[2] = bfbits(a[2] * d0[2]); o[3] = bfbits(a[3] * d0[3]);
    o[4] = bfbits(b[0] * d1[0]); o[5] = bfbits(b[1] * d1[1]);
    o[6] = bfbits(b[2] * d1[2]); o[7] = bfbits(b[3] * d1[3]);
    *(s16x8*)(h2f + (size_t)s * 8) = o;
}

// ================= Kernel 3 (agg): K=256 per barrier (2 sub-tiles), KSPLIT templ ======
// Same proven swizzle geometry as before; halves the vmcnt(0)+barrier drain count.
template <int KSPLIT>
__global__ __launch_bounds__(256, 4) void agg_kernel(const float* __restrict__ adj,
                                                     const unsigned short* __restrict__ h2f,
                                                     const float* __restrict__ dinv,
                                                     const float* __restrict__ bias,
                                                     float* __restrict__ dst) {
    constexpr int KS    = NN / KSPLIT;
    constexpr int ITERS = KS / 256;                  // 2 x 128-K sub-tiles per iter
    __shared__ short lds_a[2][2][16 * 16 * 8];       // [buf][subtile][slot*8 shorts]

    const int tid  = threadIdx.x;
    const int lane = tid & 63;
    const int wave = tid >> 6;
    const int r    = lane & 15;
    const int q    = lane >> 4;
    const int m0   = blockIdx.x << 4;
    const int k0   = blockIdx.y * KS;

    // staging: thread covers rows (tid>>5) and 8+(tid>>5), floats (tid&31)*4..+4
    const int row0 = tid >> 5;
    const int off0 = (tid & 31) << 2;
    const int cd   = (tid & 31) >> 1;   // dest 16B chunk (8 bf16)
    const int hh   = tid & 1;           // which half of the chunk
    const int so0  = ((row0 << 4) + (cd ^ row0)) * 8 + hh * 4;
    const int so1  = (((8 + row0) << 4) + (cd ^ (8 + row0))) * 8 + hh * 4;

    const float* ap0 = adj + (size_t)(m0 + row0) * NN + k0 + off0;
    const float* ap1 = adj + (size_t)(m0 + 8 + row0) * NN + k0 + off0;

    // B: frags f = wave*2, wave*2+1; contiguous 1 KB per (f, kgrp)
    const unsigned short* bb0 = h2f + (((size_t)(wave * 2)     * 256 + (k0 >> 5)) * 64 + lane) * 8;
    const unsigned short* bb1 = h2f + (((size_t)(wave * 2 + 1) * 256 + (k0 >> 5)) * 64 + lane) * 8;

    f32x4 acc0 = {0.f, 0.f, 0.f, 0.f};
    f32x4 acc1 = {0.f, 0.f, 0.f, 0.f};

    // prologue: stage iter 0 (both sub-tiles)
    {
        f32x4 a0 = *(const f32x4*)(ap0);
        f32x4 a1 = *(const f32x4*)(ap1);
        f32x4 b0 = *(const f32x4*)(ap0 + 128);
        f32x4 b1 = *(const f32x4*)(ap1 + 128);
        *(s16x4*)&lds_a[0][0][so0] = cvt4(a0);
        *(s16x4*)&lds_a[0][0][so1] = cvt4(a1);
        *(s16x4*)&lds_a[0][1][so0] = cvt4(b0);
        *(s16x4*)&lds_a[0][1][so1] = cvt4(b1);
    }
    __syncthreads();

    for (int t = 0; t < ITERS; ++t) {
        const short* lc0 = lds_a[t & 1][0];
        const short* lc1 = lds_a[t & 1][1];

        // B loads FIRST (L2-resident; MFMA's vmcnt wait then excludes the A prefetch)
        s16x8 br0[8], br1[8];
        #pragma unroll
        for (int s = 0; s < 8; ++s) {
            br0[s] = *(const s16x8*)(bb0 + (size_t)(t * 8 + s) * 512);
            br1[s] = *(const s16x8*)(bb1 + (size_t)(t * 8 + s) * 512);
        }
        // A prefetch for next iter (HBM; consumed only after the MFMAs)
        f32x4 v0a, v1a, v0b, v1b;
        if (t + 1 < ITERS) {
            v0a = *(const f32x4*)(ap0 + (t + 1) * 256);
            v1a = *(const f32x4*)(ap1 + (t + 1) * 256);
            v0b = *(const f32x4*)(ap0 + (t + 1) * 256 + 128);
            v1b = *(const f32x4*)(ap1 + (t + 1) * 256 + 128);
        }
        // 16 MFMAs per drain window: A frag = one swizzled ds_read_b128 each
        #pragma unroll
        for (int s = 0; s < 4; ++s) {
            const int slot = (r << 4) + (((s << 2) + q) ^ r);
            s16x8 af = *(const s16x8*)(lc0 + slot * 8);
            acc0 = __builtin_amdgcn_mfma_f32_16x16x32_bf16(af, br0[s], acc0, 0, 0, 0);
            acc1 = __builtin_amdgcn_mfma_f32_16x16x32_bf16(af, br1[s], acc1, 0, 0, 0);
        }
        #pragma unroll
        for (int s = 0; s < 4; ++s) {
            const int slot = (r << 4) + (((s << 2) + q) ^ r);
            s16x8 af = *(const s16x8*)(lc1 + slot * 8);
            acc0 = __builtin_amdgcn_mfma_f32_16x16x32_bf16(af, br0[4 + s], acc0, 0, 0, 0);
            acc1 = __builtin_amdgcn_mfma_f32_16x16x32_bf16(af, br1[4 + s], acc1, 0, 0, 0);
        }
        if (t + 1 < ITERS) {
            short* ln0 = (short*)lds_a[(t + 1) & 1][0];
            short* ln1 = (short*)lds_a[(t + 1) & 1][1];
            *(s16x4*)(ln0 + so0) = cvt4(v0a);
            *(s16x4*)(ln0 + so1) = cvt4(v1a);
            *(s16x4*)(ln1 + so0) = cvt4(v0b);
            *(s16x4*)(ln1 + so1) = cvt4(v1b);
        }
        __syncthreads();
    }

    // C/D: col = lane&15 (n), row = q*4+rr (m)
    #pragma unroll
    for (int rr = 0; rr < 4; ++rr) {
        const int m = m0 + (q << 2) + rr;
        const int n = (wave << 5) + r;
        if (KSPLIT == 1) {
            const float dv = dinv[m];
            dst[(size_t)m * DD + n]      = acc0[rr] * dv + bias[n];
            dst[(size_t)m * DD + n + 16] = acc1[rr] * dv + bias[n + 16];
        } else {
            float* p = dst + (size_t)blockIdx.y * NN * DD;
            p[(size_t)m * DD + n]      = acc0[rr];
            p[(size_t)m * DD + n + 16] = acc1[rr];
        }
    }
}

// ================= Kernel 4: out = dinv[m]*(p0+p1) + bias ============================
__global__ __launch_bounds__(256) void reduce_kernel(const float* __restrict__ part,
                                                     const float* __restrict__ dinv,
                                                     const float* __restrict__ bias,
                                                     float* __restrict__ out) {
    const int idx = blockIdx.x * 256 + threadIdx.x;   // f32x4 index, NN*DD/4 total
    const f32x4 a = ((const f32x4*)part)[idx];
    const f32x4 b = ((const f32x4*)part)[idx + NN * DD / 4];
    const float dv = dinv[idx >> 5];
    const f32x4 bi = *(const f32x4*)(bias + ((idx & 31) << 2));
    f32x4 s = a + b;
    f32x4 o;
    o[0] = s[0] * dv + bi[0]; o[1] = s[1] * dv + bi[1];
    o[2] = s[2] * dv + bi[2]; o[3] = s[3] * dv + bi[3];
    ((f32x4*)out)[idx] = o;
}

// ================= FALLBACK (small workspace): proven 3-kernel path ==================
__global__ __launch_bounds__(256) void deg_kernel(const float* __restrict__ adj,
                                                  float* __restrict__ dinv) {
    const int lane = threadIdx.x & 63;
    const int row  = (blockIdx.x << 2) + (threadIdx.x >> 6);
    const float* r = adj + (size_t)row * NN;
    f32x4 s = {0.f, 0.f, 0.f, 0.f};
    #pragma unroll 4
    for (int it = 0; it < 32; ++it) {
        f32x4 v = *(const f32x4*)(r + it * 256 + (lane << 2));
        s += v;
    }
    float sum = s[0] + s[1] + s[2] + s[3];
    #pragma unroll
    for (int off = 32; off; off >>= 1) sum += __shfl_xor(sum, off, 64);
    if (lane == 0) dinv[row] = (sum > 0.f) ? rsqrtf(sum) : 0.f;
}

__global__ __launch_bounds__(256) void proj_kernel(const float* __restrict__ x,
                                                   const float* __restrict__ w,
                                                   const float* __restrict__ dinv,
                                                   unsigned short* __restrict__ h2f) {
    __shared__ short lds_w[128 * WST];
    const int tid  = threadIdx.x;
    const int lane = tid & 63;
    const int wave = tid >> 6;
    const int j0   = blockIdx.x << 4;
    const int n0   = wave << 5;
    const int r    = lane & 15;
    const int q    = lane >> 4;
    #pragma unroll
    for (int i = 0; i < 16; ++i) {
        int gi = i * 256 + tid;
        int k  = gi >> 5;
        int n4 = (gi & 31) << 2;
        f32x4 v = *(const f32x4*)(w + (size_t)k * DD + n4);
        *(s16x4*)&lds_w[k * WST + n4] = cvt4(v);
    }
    __syncthreads();
    const float* xp = x + (size_t)(j0 + r) * DD + (q << 3);
    f32x4 acc0 = {0.f, 0.f, 0.f, 0.f};
    f32x4 acc1 = {0.f, 0.f, 0.f, 0.f};
    #pragma unroll
    for (int k = 0; k < DD; k += 32) {
        f32x4 a0 = *(const f32x4*)(xp + k);
        f32x4 a1 = *(const f32x4*)(xp + k + 4);
        s16x8 af = cvt8(a0, a1);
        const int kb = k + (q << 3);
        s16x8 b0, b1;
        #pragma unroll
        for (int jj = 0; jj < 8; ++jj) {
            b0[jj] = lds_w[(kb + jj) * WST + n0 + r];
            b1[jj] = lds_w[(kb + jj) * WST + n0 + 16 + r];
        }
        acc0 = __builtin_amdgcn_mfma_f32_16x16x32_bf16(af, b0, acc0, 0, 0, 0);
        acc1 = __builtin_amdgcn_mfma_f32_16x16x32_bf16(af, b1, acc1, 0, 0, 0);
    }
    #pragma unroll
    for (int rr = 0; rr < 4; ++rr) {
        const int j = j0 + (q << 2) + rr;
        const float dv = dinv[j];
        const int kg = j >> 5, qp = (j >> 3) & 3, jj = j & 7;
        #pragma unroll
        for (int half = 0; half < 2; ++half) {
            const int n = n0 + half * 16 + r;
            const int f = n >> 4;
            const int lanep = qp * 16 + (n & 15);
            const float v = (half ? acc1[rr] : acc0[rr]) * dv;
            h2f[((((size_t)f << 8) + kg) << 6 | lanep) * 8 + jj] = (unsigned short)bfbits(v);
        }
    }
}

extern "C" void kernel_launch(void* const* d_in, const int* in_sizes, int n_in,
                              void* d_out, int out_size, void* d_ws, size_t ws_size,
                              hipStream_t stream) {
    const float* x    = (const float*)d_in[0];   // [8192][128]
    const float* adj  = (const float*)d_in[1];   // [8192][8192]
    const float* w    = (const float*)d_in[2];   // [128][128]
    const float* bias = (const float*)d_in[3];   // [128]
    float* out = (float*)d_out;                  // [8192][128]

    // ws layout: dinv 32KB | h2f 2MB | hU 4MB | part 2x4MB
    float* dinv         = (float*)d_ws;
    unsigned short* h2f = (unsigned short*)((char*)d_ws + 32 * 1024);
    float* hU           = (float*)((char*)d_ws + 32 * 1024 + 2 * 1024 * 1024);
    float* part         = (float*)((char*)d_ws + 32 * 1024 + 6 * 1024 * 1024);
    const size_t need2 = 32 * 1024 + 6 * 1024 * 1024 + (size_t)2 * NN * DD * sizeof(float);

    if (ws_size >= need2) {
        prep2_kernel<<<2560, 256, 0, stream>>>(adj, x, w, dinv, hU);
        scale_kernel<<<512, 256, 0, stream>>>(hU, dinv, h2f);
        agg_kernel<2><<<dim3(NN / 16, 2), 256, 0, stream>>>(adj, h2f, dinv, bias, part);
        reduce_kernel<<<NN * DD / 4 / 256, 256, 0, stream>>>(part, dinv, bias, out);
    } else {
        deg_kernel<<<NN / 4, 256, 0, stream>>>(adj, dinv);
        proj_kernel<<<NN / 16, 256, 0, stream>>>(x, w, dinv, h2f);
        agg_kernel<1><<<dim3(NN / 16, 1), 256, 0, stream>>>(adj, h2f, dinv, bias, out);
    }
}

// Round 3
// 441.509 us; speedup vs baseline: 1.0358x; 1.0218x over previous
//
#include <hip/hip_runtime.h>
#include <hip/hip_bf16.h>

#define NN 8192
#define DD 128

typedef __attribute__((ext_vector_type(4))) float f32x4;
typedef __attribute__((ext_vector_type(8))) short s16x8;
typedef __attribute__((ext_vector_type(4))) short s16x4;

__device__ inline short bfbits(float f) {
    // fp32 -> bf16 (RNE) bit pattern
    unsigned u = __builtin_bit_cast(unsigned, f);
    u += 0x7fffu + ((u >> 16) & 1u);
    return (short)(u >> 16);
}

__device__ inline s16x4 cvt4(f32x4 a) {
    s16x4 r;
    r[0] = bfbits(a[0]); r[1] = bfbits(a[1]); r[2] = bfbits(a[2]); r[3] = bfbits(a[3]);
    return r;
}

__device__ inline s16x8 cvt8(f32x4 a, f32x4 b) {
    s16x8 r;
    r[0] = bfbits(a[0]); r[1] = bfbits(a[1]); r[2] = bfbits(a[2]); r[3] = bfbits(a[3]);
    r[4] = bfbits(b[0]); r[5] = bfbits(b[1]); r[6] = bfbits(b[2]); r[7] = bfbits(b[3]);
    return r;
}

// -------- Kernel 1: row degree + dinv (streaming, coalesced; at read floor) --------
__global__ __launch_bounds__(256) void deg_kernel(const float* __restrict__ adj,
                                                  float* __restrict__ dinv) {
    const int lane = threadIdx.x & 63;
    const int row  = (blockIdx.x << 2) + (threadIdx.x >> 6);
    const float* r = adj + (size_t)row * NN;

    f32x4 s = {0.f, 0.f, 0.f, 0.f};
    #pragma unroll 4
    for (int it = 0; it < 32; ++it) {
        f32x4 v = *(const f32x4*)(r + it * 256 + (lane << 2));
        s += v;
    }
    float sum = s[0] + s[1] + s[2] + s[3];
    #pragma unroll
    for (int off = 32; off; off >>= 1) sum += __shfl_xor(sum, off, 64);
    if (lane == 0) dinv[row] = (sum > 0.f) ? rsqrtf(sum) : 0.f;
}

// -------- Kernel 2: h2f = dinv[j]*(x@W)[j][n] stored in MFMA B-fragment order ----
// h2f element layout: [frag f = n>>4][kgrp = j>>5][lane = ((j>>3)&3)*16 + (n&15)][jj = j&7]
// so agg's B-load per wave is one contiguous 1 KB region per (f, kgrp).
#define WST 132  // LDS stride (shorts) for w tile: kills 8-way bank conflicts
__global__ __launch_bounds__(256) void proj_kernel(const float* __restrict__ x,
                                                   const float* __restrict__ w,
                                                   const float* __restrict__ dinv,
                                                   unsigned short* __restrict__ h2f) {
    __shared__ short lds_w[128 * WST];
    const int tid  = threadIdx.x;
    const int lane = tid & 63;
    const int wave = tid >> 6;
    const int j0   = blockIdx.x << 4;
    const int n0   = wave << 5;
    const int r    = lane & 15;
    const int q    = lane >> 4;

    // stage W -> LDS bf16, coalesced f32x4
    #pragma unroll
    for (int i = 0; i < 16; ++i) {
        int gi = i * 256 + tid;
        int k  = gi >> 5;
        int n4 = (gi & 31) << 2;
        f32x4 v = *(const f32x4*)(w + (size_t)k * DD + n4);
        *(s16x4*)&lds_w[k * WST + n4] = cvt4(v);
    }
    __syncthreads();

    const float* xp = x + (size_t)(j0 + r) * DD + (q << 3);

    f32x4 acc0 = {0.f, 0.f, 0.f, 0.f};
    f32x4 acc1 = {0.f, 0.f, 0.f, 0.f};

    #pragma unroll
    for (int k = 0; k < DD; k += 32) {
        f32x4 a0 = *(const f32x4*)(xp + k);
        f32x4 a1 = *(const f32x4*)(xp + k + 4);
        s16x8 af = cvt8(a0, a1);

        const int kb = k + (q << 3);
        s16x8 b0, b1;
        #pragma unroll
        for (int jj = 0; jj < 8; ++jj) {
            b0[jj] = lds_w[(kb + jj) * WST + n0 + r];
            b1[jj] = lds_w[(kb + jj) * WST + n0 + 16 + r];
        }
        acc0 = __builtin_amdgcn_mfma_f32_16x16x32_bf16(af, b0, acc0, 0, 0, 0);
        acc1 = __builtin_amdgcn_mfma_f32_16x16x32_bf16(af, b1, acc1, 0, 0, 0);
    }

    // C/D: col = lane&15 (n), row = q*4+rr (j). Scatter into fragment order.
    #pragma unroll
    for (int rr = 0; rr < 4; ++rr) {
        const int j = j0 + (q << 2) + rr;
        const float dv = dinv[j];
        const int kg = j >> 5, qp = (j >> 3) & 3, jj = j & 7;
        #pragma unroll
        for (int half = 0; half < 2; ++half) {
            const int n = n0 + half * 16 + r;
            const int f = n >> 4;
            const int lanep = qp * 16 + (n & 15);
            const float v = (half ? acc1[rr] : acc0[rr]) * dv;
            h2f[((((size_t)f << 8) + kg) << 6 | lanep) * 8 + jj] = (unsigned short)bfbits(v);
        }
    }
}

// -------- Kernel 3: partial[m][n] = sum_{k in split} adj[m][k]*h2[k][n] --------
// LDS-staged A (bf16, XOR-swizzled chunks, double-buffered), fragment-order B loads.
// ONLY change vs the proven 439us version: __launch_bounds__(256,4) -> (256,6).
// Caps VGPR at 85 (body needs ~70 by hand count) => 6-7 resident blocks/CU instead
// of 4-5, giving the CU more independent barrier-drain phases to interleave.
template <int KSPLIT>
__global__ __launch_bounds__(256, 6) void agg_kernel(const float* __restrict__ adj,
                                                     const unsigned short* __restrict__ h2f,
                                                     const float* __restrict__ dinv,
                                                     const float* __restrict__ bias,
                                                     float* __restrict__ dst) {
    constexpr int KS    = NN / KSPLIT;
    constexpr int TILES = KS / 128;
    __shared__ short lds_a[2][16 * 16 * 8];  // 2 x 4 KB: [buf][slot*8 shorts]

    const int tid  = threadIdx.x;
    const int lane = tid & 63;
    const int wave = tid >> 6;
    const int r    = lane & 15;
    const int q    = lane >> 4;
    const int m0   = blockIdx.x << 4;
    const int k0   = blockIdx.y * KS;

    // staging: thread covers rows (tid>>5) and 8+(tid>>5), floats (tid&31)*4..+4
    const int row0 = tid >> 5;
    const int off0 = (tid & 31) << 2;
    const int cd   = (tid & 31) >> 1;   // dest 16B chunk (8 bf16)
    const int hh   = tid & 1;           // which half of the chunk
    const int so0  = ((row0 << 4) + (cd ^ row0)) * 8 + hh * 4;
    const int so1  = (((8 + row0) << 4) + (cd ^ (8 + row0))) * 8 + hh * 4;

    const float* ap0 = adj + (size_t)(m0 + row0) * NN + k0 + off0;
    const float* ap1 = adj + (size_t)(m0 + 8 + row0) * NN + k0 + off0;

    // B: frags f = wave*2, wave*2+1; contiguous 1 KB per (f, kgrp)
    const unsigned short* bb0 = h2f + (((size_t)(wave * 2)     * 256 + (k0 >> 5)) * 64 + lane) * 8;
    const unsigned short* bb1 = h2f + (((size_t)(wave * 2 + 1) * 256 + (k0 >> 5)) * 64 + lane) * 8;

    f32x4 acc0 = {0.f, 0.f, 0.f, 0.f};
    f32x4 acc1 = {0.f, 0.f, 0.f, 0.f};

    // prologue: stage tile 0
    {
        f32x4 v0 = *(const f32x4*)(ap0);
        f32x4 v1 = *(const f32x4*)(ap1);
        *(s16x4*)&lds_a[0][so0] = cvt4(v0);
        *(s16x4*)&lds_a[0][so1] = cvt4(v1);
    }
    __syncthreads();

    for (int t = 0; t < TILES; ++t) {
        const short* lcur = lds_a[t & 1];
        short* lnxt = (short*)lds_a[(t + 1) & 1];

        // B loads for this tile (L2-resident, issued first => consumed first in vmcnt FIFO)
        s16x8 br0[4], br1[4];
        #pragma unroll
        for (int s = 0; s < 4; ++s) {
            br0[s] = *(const s16x8*)(bb0 + (size_t)(t * 4 + s) * 512);
            br1[s] = *(const s16x8*)(bb1 + (size_t)(t * 4 + s) * 512);
        }
        // staging loads for next tile (HBM; consumed only after the MFMAs)
        f32x4 v0, v1;
        if (t + 1 < TILES) {
            v0 = *(const f32x4*)(ap0 + (t + 1) * 128);
            v1 = *(const f32x4*)(ap1 + (t + 1) * 128);
        }
        // compute on current tile: A frag = one swizzled ds_read_b128
        #pragma unroll
        for (int s = 0; s < 4; ++s) {
            const int slot = (r << 4) + (((s << 2) + q) ^ r);
            s16x8 af = *(const s16x8*)(lcur + slot * 8);
            acc0 = __builtin_amdgcn_mfma_f32_16x16x32_bf16(af, br0[s], acc0, 0, 0, 0);
            acc1 = __builtin_amdgcn_mfma_f32_16x16x32_bf16(af, br1[s], acc1, 0, 0, 0);
        }
        if (t + 1 < TILES) {
            *(s16x4*)(lnxt + so0) = cvt4(v0);
            *(s16x4*)(lnxt + so1) = cvt4(v1);
        }
        __syncthreads();
    }

    // C/D: col = lane&15 (n), row = q*4+rr (m)
    #pragma unroll
    for (int rr = 0; rr < 4; ++rr) {
        const int m = m0 + (q << 2) + rr;
        const int n = (wave << 5) + r;
        if (KSPLIT == 1) {
            const float dv = dinv[m];
            dst[(size_t)m * DD + n]      = acc0[rr] * dv + bias[n];
            dst[(size_t)m * DD + n + 16] = acc1[rr] * dv + bias[n + 16];
        } else {
            float* p = dst + (size_t)blockIdx.y * NN * DD;
            p[(size_t)m * DD + n]      = acc0[rr];
            p[(size_t)m * DD + n + 16] = acc1[rr];
        }
    }
}

// -------- Kernel 4: out = dinv[m]*(p0+p1) + bias (only for KSPLIT=2 path) --------
__global__ __launch_bounds__(256) void reduce_kernel(const float* __restrict__ part,
                                                     const float* __restrict__ dinv,
                                                     const float* __restrict__ bias,
                                                     float* __restrict__ out) {
    const int idx = blockIdx.x * 256 + threadIdx.x;   // f32x4 index, NN*DD/4 total
    const f32x4 a = ((const f32x4*)part)[idx];
    const f32x4 b = ((const f32x4*)part)[idx + NN * DD / 4];
    const float dv = dinv[idx >> 5];
    const f32x4 bi = *(const f32x4*)(bias + ((idx & 31) << 2));
    f32x4 s = a + b;
    f32x4 o;
    o[0] = s[0] * dv + bi[0]; o[1] = s[1] * dv + bi[1];
    o[2] = s[2] * dv + bi[2]; o[3] = s[3] * dv + bi[3];
    ((f32x4*)out)[idx] = o;
}

extern "C" void kernel_launch(void* const* d_in, const int* in_sizes, int n_in,
                              void* d_out, int out_size, void* d_ws, size_t ws_size,
                              hipStream_t stream) {
    const float* x    = (const float*)d_in[0];   // [8192][128]
    const float* adj  = (const float*)d_in[1];   // [8192][8192]
    const float* w    = (const float*)d_in[2];   // [128][128]
    const float* bias = (const float*)d_in[3];   // [128]
    float* out = (float*)d_out;                  // [8192][128]

    // ws layout: dinv (32 KB) | h2f bf16 fragment-order (2 MB) | partials (2 x 4 MB)
    float* dinv = (float*)d_ws;
    unsigned short* h2f = (unsigned short*)((char*)d_ws + 32 * 1024);
    float* part = (float*)((char*)d_ws + 32 * 1024 + 2 * 1024 * 1024);
    const size_t need2 = 32 * 1024 + 2 * 1024 * 1024 + (size_t)2 * NN * DD * sizeof(float);

    deg_kernel<<<NN / 4, 256, 0, stream>>>(adj, dinv);
    proj_kernel<<<NN / 16, 256, 0, stream>>>(x, w, dinv, h2f);

    if (ws_size >= need2) {
        agg_kernel<2><<<dim3(NN / 16, 2), 256, 0, stream>>>(adj, h2f, dinv, bias, part);
        reduce_kernel<<<NN * DD / 4 / 256, 256, 0, stream>>>(part, dinv, bias, out);
    } else {
        agg_kernel<1><<<dim3(NN / 16, 1), 256, 0, stream>>>(adj, h2f, dinv, bias, out);
    }
}

// Round 4
// 425.583 us; speedup vs baseline: 1.0745x; 1.0374x over previous
//
#include <hip/hip_runtime.h>
#include <hip/hip_bf16.h>

#define NN 8192
#define DD 128

typedef __attribute__((ext_vector_type(4))) float f32x4;
typedef __attribute__((ext_vector_type(8))) short s16x8;
typedef __attribute__((ext_vector_type(4))) short s16x4;

__device__ inline short bfbits(float f) {
    // fp32 -> bf16 (RNE) bit pattern
    unsigned u = __builtin_bit_cast(unsigned, f);
    u += 0x7fffu + ((u >> 16) & 1u);
    return (short)(u >> 16);
}

__device__ inline s16x4 cvt4(f32x4 a) {
    s16x4 r;
    r[0] = bfbits(a[0]); r[1] = bfbits(a[1]); r[2] = bfbits(a[2]); r[3] = bfbits(a[3]);
    return r;
}

__device__ inline s16x8 cvt8(f32x4 a, f32x4 b) {
    s16x8 r;
    r[0] = bfbits(a[0]); r[1] = bfbits(a[1]); r[2] = bfbits(a[2]); r[3] = bfbits(a[3]);
    r[4] = bfbits(b[0]); r[5] = bfbits(b[1]); r[6] = bfbits(b[2]); r[7] = bfbits(b[3]);
    return r;
}

// -------- Kernel 1: row degree + dinv (streaming, coalesced; at read floor) --------
__global__ __launch_bounds__(256) void deg_kernel(const float* __restrict__ adj,
                                                  float* __restrict__ dinv) {
    const int lane = threadIdx.x & 63;
    const int row  = (blockIdx.x << 2) + (threadIdx.x >> 6);
    const float* r = adj + (size_t)row * NN;

    f32x4 s = {0.f, 0.f, 0.f, 0.f};
    #pragma unroll 4
    for (int it = 0; it < 32; ++it) {
        f32x4 v = *(const f32x4*)(r + it * 256 + (lane << 2));
        s += v;
    }
    float sum = s[0] + s[1] + s[2] + s[3];
    #pragma unroll
    for (int off = 32; off; off >>= 1) sum += __shfl_xor(sum, off, 64);
    if (lane == 0) dinv[row] = (sum > 0.f) ? rsqrtf(sum) : 0.f;
}

// -------- Kernel 2: h2f = dinv[j]*(x@W)[j][n] stored in MFMA B-fragment order ----
// h2f element layout: [frag f = n>>4][kgrp = j>>5][lane = ((j>>3)&3)*16 + (n&15)][jj = j&7]
// so agg's B-load per wave is one contiguous 1 KB region per (f, kgrp).
#define WST 132  // LDS stride (shorts) for w tile: kills 8-way bank conflicts
__global__ __launch_bounds__(256) void proj_kernel(const float* __restrict__ x,
                                                   const float* __restrict__ w,
                                                   const float* __restrict__ dinv,
                                                   unsigned short* __restrict__ h2f) {
    __shared__ short lds_w[128 * WST];
    const int tid  = threadIdx.x;
    const int lane = tid & 63;
    const int wave = tid >> 6;
    const int j0   = blockIdx.x << 4;
    const int n0   = wave << 5;
    const int r    = lane & 15;
    const int q    = lane >> 4;

    // stage W -> LDS bf16, coalesced f32x4
    #pragma unroll
    for (int i = 0; i < 16; ++i) {
        int gi = i * 256 + tid;
        int k  = gi >> 5;
        int n4 = (gi & 31) << 2;
        f32x4 v = *(const f32x4*)(w + (size_t)k * DD + n4);
        *(s16x4*)&lds_w[k * WST + n4] = cvt4(v);
    }
    __syncthreads();

    const float* xp = x + (size_t)(j0 + r) * DD + (q << 3);

    f32x4 acc0 = {0.f, 0.f, 0.f, 0.f};
    f32x4 acc1 = {0.f, 0.f, 0.f, 0.f};

    #pragma unroll
    for (int k = 0; k < DD; k += 32) {
        f32x4 a0 = *(const f32x4*)(xp + k);
        f32x4 a1 = *(const f32x4*)(xp + k + 4);
        s16x8 af = cvt8(a0, a1);

        const int kb = k + (q << 3);
        s16x8 b0, b1;
        #pragma unroll
        for (int jj = 0; jj < 8; ++jj) {
            b0[jj] = lds_w[(kb + jj) * WST + n0 + r];
            b1[jj] = lds_w[(kb + jj) * WST + n0 + 16 + r];
        }
        acc0 = __builtin_amdgcn_mfma_f32_16x16x32_bf16(af, b0, acc0, 0, 0, 0);
        acc1 = __builtin_amdgcn_mfma_f32_16x16x32_bf16(af, b1, acc1, 0, 0, 0);
    }

    // C/D: col = lane&15 (n), row = q*4+rr (j). Scatter into fragment order.
    #pragma unroll
    for (int rr = 0; rr < 4; ++rr) {
        const int j = j0 + (q << 2) + rr;
        const float dv = dinv[j];
        const int kg = j >> 5, qp = (j >> 3) & 3, jj = j & 7;
        #pragma unroll
        for (int half = 0; half < 2; ++half) {
            const int n = n0 + half * 16 + r;
            const int f = n >> 4;
            const int lanep = qp * 16 + (n & 15);
            const float v = (half ? acc1[rr] : acc0[rr]) * dv;
            h2f[((((size_t)f << 8) + kg) << 6 | lanep) * 8 + jj] = (unsigned short)bfbits(v);
        }
    }
}

// -------- Kernel 3a (agg32): BM=32, B-register reuse across two 16-row subtiles ----
// Each wave loads the SAME 8 B frag-regions per K-tile as BM=16, but feeds them to
// TWO A fragments (rows 0-15 and 16-31) with 4 accumulators => per-output-row L2
// B-traffic halves (1 GB -> 512 MB). Staging/swizzle/B-first ordering identical to
// the proven pattern, replicated per 16-row subtile. KSPLIT=4 keeps 1024 blocks.
template <int KSPLIT>
__global__ __launch_bounds__(256, 4) void agg32_kernel(const float* __restrict__ adj,
                                                       const unsigned short* __restrict__ h2f,
                                                       float* __restrict__ dst) {
    constexpr int KS    = NN / KSPLIT;
    constexpr int TILES = KS / 128;
    __shared__ short lds_a[2][2][16 * 16 * 8];  // [buf][subtile(16 rows)][slot*8 shorts]

    const int tid  = threadIdx.x;
    const int lane = tid & 63;
    const int wave = tid >> 6;
    const int r    = lane & 15;
    const int q    = lane >> 4;
    const int m0   = blockIdx.x << 5;
    const int k0   = blockIdx.y * KS;

    // staging: thread covers rows row0, +8, +16, +24; floats (tid&31)*4..+4
    const int row0 = tid >> 5;              // 0..7
    const int off0 = (tid & 31) << 2;
    const int cd   = (tid & 31) >> 1;       // dest 16B chunk (8 bf16)
    const int hh   = tid & 1;               // which half of the chunk
    const int so0  = ((row0 << 4) + (cd ^ row0)) * 8 + hh * 4;              // rows 0-7 / 16-23
    const int so1  = (((8 + row0) << 4) + (cd ^ (8 + row0))) * 8 + hh * 4;  // rows 8-15 / 24-31

    const float* ap0 = adj + (size_t)(m0 + row0)      * NN + k0 + off0;
    const float* ap1 = adj + (size_t)(m0 + 8 + row0)  * NN + k0 + off0;
    const float* ap2 = adj + (size_t)(m0 + 16 + row0) * NN + k0 + off0;
    const float* ap3 = adj + (size_t)(m0 + 24 + row0) * NN + k0 + off0;

    // B: frags f = wave*2, wave*2+1; contiguous 1 KB per (f, kgrp)
    const unsigned short* bb0 = h2f + (((size_t)(wave * 2)     * 256 + (k0 >> 5)) * 64 + lane) * 8;
    const unsigned short* bb1 = h2f + (((size_t)(wave * 2 + 1) * 256 + (k0 >> 5)) * 64 + lane) * 8;

    f32x4 acc00 = {0.f, 0.f, 0.f, 0.f};  // rows 0-15, n..n+?
    f32x4 acc01 = {0.f, 0.f, 0.f, 0.f};
    f32x4 acc10 = {0.f, 0.f, 0.f, 0.f};  // rows 16-31
    f32x4 acc11 = {0.f, 0.f, 0.f, 0.f};

    // prologue: stage tile 0
    {
        f32x4 v0 = *(const f32x4*)(ap0);
        f32x4 v1 = *(const f32x4*)(ap1);
        f32x4 v2 = *(const f32x4*)(ap2);
        f32x4 v3 = *(const f32x4*)(ap3);
        *(s16x4*)&lds_a[0][0][so0] = cvt4(v0);
        *(s16x4*)&lds_a[0][0][so1] = cvt4(v1);
        *(s16x4*)&lds_a[0][1][so0] = cvt4(v2);
        *(s16x4*)&lds_a[0][1][so1] = cvt4(v3);
    }
    __syncthreads();

    for (int t = 0; t < TILES; ++t) {
        const short* lc0 = lds_a[t & 1][0];
        const short* lc1 = lds_a[t & 1][1];

        // B loads for this tile (L2-resident, issued first => consumed first in vmcnt FIFO)
        s16x8 br0[4], br1[4];
        #pragma unroll
        for (int s = 0; s < 4; ++s) {
            br0[s] = *(const s16x8*)(bb0 + (size_t)(t * 4 + s) * 512);
            br1[s] = *(const s16x8*)(bb1 + (size_t)(t * 4 + s) * 512);
        }
        // staging loads for next tile (HBM; consumed only after the MFMAs)
        f32x4 v0, v1, v2, v3;
        if (t + 1 < TILES) {
            v0 = *(const f32x4*)(ap0 + (t + 1) * 128);
            v1 = *(const f32x4*)(ap1 + (t + 1) * 128);
            v2 = *(const f32x4*)(ap2 + (t + 1) * 128);
            v3 = *(const f32x4*)(ap3 + (t + 1) * 128);
        }
        // compute: per s, two swizzled A ds_read_b128 (row halves) share the B regs
        #pragma unroll
        for (int s = 0; s < 4; ++s) {
            const int slot = (r << 4) + (((s << 2) + q) ^ r);
            s16x8 afA = *(const s16x8*)(lc0 + slot * 8);
            s16x8 afB = *(const s16x8*)(lc1 + slot * 8);
            acc00 = __builtin_amdgcn_mfma_f32_16x16x32_bf16(afA, br0[s], acc00, 0, 0, 0);
            acc01 = __builtin_amdgcn_mfma_f32_16x16x32_bf16(afA, br1[s], acc01, 0, 0, 0);
            acc10 = __builtin_amdgcn_mfma_f32_16x16x32_bf16(afB, br0[s], acc10, 0, 0, 0);
            acc11 = __builtin_amdgcn_mfma_f32_16x16x32_bf16(afB, br1[s], acc11, 0, 0, 0);
        }
        if (t + 1 < TILES) {
            short* ln0 = (short*)lds_a[(t + 1) & 1][0];
            short* ln1 = (short*)lds_a[(t + 1) & 1][1];
            *(s16x4*)(ln0 + so0) = cvt4(v0);
            *(s16x4*)(ln0 + so1) = cvt4(v1);
            *(s16x4*)(ln1 + so0) = cvt4(v2);
            *(s16x4*)(ln1 + so1) = cvt4(v3);
        }
        __syncthreads();
    }

    // C/D: col = lane&15 (n), row = q*4+rr (m within subtile)
    float* p = dst + (size_t)blockIdx.y * NN * DD;
    #pragma unroll
    for (int rr = 0; rr < 4; ++rr) {
        const int mA = m0 + (q << 2) + rr;
        const int mB = mA + 16;
        const int n  = (wave << 5) + r;
        p[(size_t)mA * DD + n]      = acc00[rr];
        p[(size_t)mA * DD + n + 16] = acc01[rr];
        p[(size_t)mB * DD + n]      = acc10[rr];
        p[(size_t)mB * DD + n + 16] = acc11[rr];
    }
}

// -------- Kernel 3b: proven BM=16 agg (R0 structure, exact) ---------------------
template <int KSPLIT>
__global__ __launch_bounds__(256, 4) void agg_kernel(const float* __restrict__ adj,
                                                     const unsigned short* __restrict__ h2f,
                                                     const float* __restrict__ dinv,
                                                     const float* __restrict__ bias,
                                                     float* __restrict__ dst) {
    constexpr int KS    = NN / KSPLIT;
    constexpr int TILES = KS / 128;
    __shared__ short lds_a[2][16 * 16 * 8];  // 2 x 4 KB: [buf][slot*8 shorts]

    const int tid  = threadIdx.x;
    const int lane = tid & 63;
    const int wave = tid >> 6;
    const int r    = lane & 15;
    const int q    = lane >> 4;
    const int m0   = blockIdx.x << 4;
    const int k0   = blockIdx.y * KS;

    const int row0 = tid >> 5;
    const int off0 = (tid & 31) << 2;
    const int cd   = (tid & 31) >> 1;
    const int hh   = tid & 1;
    const int so0  = ((row0 << 4) + (cd ^ row0)) * 8 + hh * 4;
    const int so1  = (((8 + row0) << 4) + (cd ^ (8 + row0))) * 8 + hh * 4;

    const float* ap0 = adj + (size_t)(m0 + row0) * NN + k0 + off0;
    const float* ap1 = adj + (size_t)(m0 + 8 + row0) * NN + k0 + off0;

    const unsigned short* bb0 = h2f + (((size_t)(wave * 2)     * 256 + (k0 >> 5)) * 64 + lane) * 8;
    const unsigned short* bb1 = h2f + (((size_t)(wave * 2 + 1) * 256 + (k0 >> 5)) * 64 + lane) * 8;

    f32x4 acc0 = {0.f, 0.f, 0.f, 0.f};
    f32x4 acc1 = {0.f, 0.f, 0.f, 0.f};

    {
        f32x4 v0 = *(const f32x4*)(ap0);
        f32x4 v1 = *(const f32x4*)(ap1);
        *(s16x4*)&lds_a[0][so0] = cvt4(v0);
        *(s16x4*)&lds_a[0][so1] = cvt4(v1);
    }
    __syncthreads();

    for (int t = 0; t < TILES; ++t) {
        const short* lcur = lds_a[t & 1];
        short* lnxt = (short*)lds_a[(t + 1) & 1];

        s16x8 br0[4], br1[4];
        #pragma unroll
        for (int s = 0; s < 4; ++s) {
            br0[s] = *(const s16x8*)(bb0 + (size_t)(t * 4 + s) * 512);
            br1[s] = *(const s16x8*)(bb1 + (size_t)(t * 4 + s) * 512);
        }
        f32x4 v0, v1;
        if (t + 1 < TILES) {
            v0 = *(const f32x4*)(ap0 + (t + 1) * 128);
            v1 = *(const f32x4*)(ap1 + (t + 1) * 128);
        }
        #pragma unroll
        for (int s = 0; s < 4; ++s) {
            const int slot = (r << 4) + (((s << 2) + q) ^ r);
            s16x8 af = *(const s16x8*)(lcur + slot * 8);
            acc0 = __builtin_amdgcn_mfma_f32_16x16x32_bf16(af, br0[s], acc0, 0, 0, 0);
            acc1 = __builtin_amdgcn_mfma_f32_16x16x32_bf16(af, br1[s], acc1, 0, 0, 0);
        }
        if (t + 1 < TILES) {
            *(s16x4*)(lnxt + so0) = cvt4(v0);
            *(s16x4*)(lnxt + so1) = cvt4(v1);
        }
        __syncthreads();
    }

    #pragma unroll
    for (int rr = 0; rr < 4; ++rr) {
        const int m = m0 + (q << 2) + rr;
        const int n = (wave << 5) + r;
        if (KSPLIT == 1) {
            const float dv = dinv[m];
            dst[(size_t)m * DD + n]      = acc0[rr] * dv + bias[n];
            dst[(size_t)m * DD + n + 16] = acc1[rr] * dv + bias[n + 16];
        } else {
            float* p = dst + (size_t)blockIdx.y * NN * DD;
            p[(size_t)m * DD + n]      = acc0[rr];
            p[(size_t)m * DD + n + 16] = acc1[rr];
        }
    }
}

// -------- Kernel 4a: out = dinv[m]*(p0+p1+p2+p3) + bias (KSPLIT=4 path) --------
__global__ __launch_bounds__(256) void reduce4_kernel(const float* __restrict__ part,
                                                      const float* __restrict__ dinv,
                                                      const float* __restrict__ bias,
                                                      float* __restrict__ out) {
    const int idx = blockIdx.x * 256 + threadIdx.x;   // f32x4 index, NN*DD/4 total
    const f32x4 a = ((const f32x4*)part)[idx];
    const f32x4 b = ((const f32x4*)part)[idx + NN * DD / 4];
    const f32x4 c = ((const f32x4*)part)[idx + 2 * (NN * DD / 4)];
    const f32x4 d = ((const f32x4*)part)[idx + 3 * (NN * DD / 4)];
    const float dv = dinv[idx >> 5];
    const f32x4 bi = *(const f32x4*)(bias + ((idx & 31) << 2));
    f32x4 s = (a + b) + (c + d);
    f32x4 o;
    o[0] = s[0] * dv + bi[0]; o[1] = s[1] * dv + bi[1];
    o[2] = s[2] * dv + bi[2]; o[3] = s[3] * dv + bi[3];
    ((f32x4*)out)[idx] = o;
}

// -------- Kernel 4b: out = dinv[m]*(p0+p1) + bias (KSPLIT=2 path) --------
__global__ __launch_bounds__(256) void reduce_kernel(const float* __restrict__ part,
                                                     const float* __restrict__ dinv,
                                                     const float* __restrict__ bias,
                                                     float* __restrict__ out) {
    const int idx = blockIdx.x * 256 + threadIdx.x;
    const f32x4 a = ((const f32x4*)part)[idx];
    const f32x4 b = ((const f32x4*)part)[idx + NN * DD / 4];
    const float dv = dinv[idx >> 5];
    const f32x4 bi = *(const f32x4*)(bias + ((idx & 31) << 2));
    f32x4 s = a + b;
    f32x4 o;
    o[0] = s[0] * dv + bi[0]; o[1] = s[1] * dv + bi[1];
    o[2] = s[2] * dv + bi[2]; o[3] = s[3] * dv + bi[3];
    ((f32x4*)out)[idx] = o;
}

extern "C" void kernel_launch(void* const* d_in, const int* in_sizes, int n_in,
                              void* d_out, int out_size, void* d_ws, size_t ws_size,
                              hipStream_t stream) {
    const float* x    = (const float*)d_in[0];   // [8192][128]
    const float* adj  = (const float*)d_in[1];   // [8192][8192]
    const float* w    = (const float*)d_in[2];   // [128][128]
    const float* bias = (const float*)d_in[3];   // [128]
    float* out = (float*)d_out;                  // [8192][128]

    // ws layout: dinv (32 KB) | h2f bf16 fragment-order (2 MB) | partials (up to 4 x 4 MB)
    float* dinv = (float*)d_ws;
    unsigned short* h2f = (unsigned short*)((char*)d_ws + 32 * 1024);
    float* part = (float*)((char*)d_ws + 32 * 1024 + 2 * 1024 * 1024);
    const size_t base  = 32 * 1024 + 2 * 1024 * 1024;
    const size_t need4 = base + (size_t)4 * NN * DD * sizeof(float);
    const size_t need2 = base + (size_t)2 * NN * DD * sizeof(float);

    deg_kernel<<<NN / 4, 256, 0, stream>>>(adj, dinv);
    proj_kernel<<<NN / 16, 256, 0, stream>>>(x, w, dinv, h2f);

    if (ws_size >= need4) {
        agg32_kernel<4><<<dim3(NN / 32, 4), 256, 0, stream>>>(adj, h2f, part);
        reduce4_kernel<<<NN * DD / 4 / 256, 256, 0, stream>>>(part, dinv, bias, out);
    } else if (ws_size >= need2) {
        agg_kernel<2><<<dim3(NN / 16, 2), 256, 0, stream>>>(adj, h2f, dinv, bias, part);
        reduce_kernel<<<NN * DD / 4 / 256, 256, 0, stream>>>(part, dinv, bias, out);
    } else {
        agg_kernel<1><<<dim3(NN / 16, 1), 256, 0, stream>>>(adj, h2f, dinv, bias, out);
    }
}